// Round 17
// baseline (406.315 us; speedup 1.0000x reference)
//
#include <hip/hip_runtime.h>

#define NN 50000
#define NE 800000
#define INC 32
#define HH 64
#define H2 128
#define OC 16
#define ON 17
#define NL 4
#define MEPS 1e-7f
#define LNE 1e-5f
#define NMB ((NN + 127) / 128)     /* k_mlp blocks = 391 */
#define NBW ((NL * H2 * HH + 255) / 256)   /* 128 */
#define NBH4 ((NE + 1023) / 1024)          /* 782: hist/scatter blocks, 4 edges/thread */
#define NBE8 ((NN + 7) / 8)                /* 6250: encoder, 8 nodes/block */
#define NBK  ((NN + 255) / 256)            /* 196 dst-buckets */

typedef __attribute__((ext_vector_type(8))) short bf16x8;
typedef __attribute__((ext_vector_type(4))) float f32x4;

// ---------- bf16 helpers (RNE) ----------
__device__ __forceinline__ unsigned short f2b(float x) {
    unsigned b = __float_as_uint(x);
    b += 0x7FFFu + ((b >> 16) & 1u);
    return (unsigned short)(b >> 16);
}
__device__ __forceinline__ float b2f(unsigned short u) {
    return __uint_as_float(((unsigned)u) << 16);
}

// ---------- fused pre-pass: wprep | LDS-hist (NO global atomics) | encoder ----------
// Round-16 finding: 800K returning device atomics cost ~40us at the coherence point
// (per-op write-through; replication null-result proved it's op-count-bound).
// Fix: per-block LDS histogram over 196 dst-buckets + stored local rank; global CSR
// positions derived by scans (k_bscan) -> zero global atomics in the whole pipeline.
__global__ __launch_bounds__(256) void k_pre(
    const float* __restrict__ W1, const float* __restrict__ W2,
    const float* __restrict__ nW, const float* __restrict__ gW,
    const float* __restrict__ nbp, const float* __restrict__ gb,
    unsigned short* __restrict__ w1h, unsigned short* __restrict__ w1l,
    unsigned short* __restrict__ w2h, unsigned short* __restrict__ w2l,
    unsigned short* __restrict__ whh, unsigned short* __restrict__ whl,
    float* __restrict__ bc,
    const int* __restrict__ edst, int* __restrict__ bhist, unsigned short* __restrict__ lrank,
    const float* __restrict__ x, const float* __restrict__ nodeW,
    const float* __restrict__ nodeB, float* __restrict__ h,
    unsigned short* __restrict__ hbf)
{
    __shared__ float Ws[INC * HH];
    __shared__ float bs[HH];
    __shared__ int histS[256];
    int bid = blockIdx.x, tid = threadIdx.x;
    if (bid < NBW) {
        int i = bid * 256 + tid;
        if (i < 48 * 64) {
            int j = i >> 6, k = i & 63;
            float v = 0.f;
            if (j < ON) v = nW[k * ON + j];
            else if (j < 33) v = gW[k * OC + (j - ON)];
            unsigned short hi = f2b(v);
            whh[i] = hi;
            whl[i] = f2b(v - b2f(hi));
        }
        if (i < 48) bc[i] = (i < ON) ? nbp[i] : ((i < 33) ? gb[i - ON] : 0.f);
        if (i >= NL * H2 * HH) return;
        int l = i / (H2 * HH), r = i % (H2 * HH);
        {
            int c = r / HH, k = r % HH;
            float v = W1[(size_t)l * HH * H2 + (size_t)k * H2 + c];
            unsigned short hi = f2b(v);
            w1h[i] = hi;
            w1l[i] = f2b(v - b2f(hi));
        }
        {
            int c = r / H2, k = r % H2;
            float v = W2[(size_t)l * H2 * HH + (size_t)k * HH + c];
            unsigned short hi = f2b(v);
            w2h[i] = hi;
            w2l[i] = f2b(v - b2f(hi));
        }
        return;
    }
    if (bid < NBW + NBH4) {
        int blk = bid - NBW;
        histS[tid] = 0;
        __syncthreads();
        int base = blk * 1024 + tid;
        #pragma unroll
        for (int k = 0; k < 4; ++k) {
            int e = base + k * 256;
            if (e < NE) {
                int r = atomicAdd(&histS[edst[e] >> 8], 1);   // LDS atomic: cheap
                lrank[e] = (unsigned short)r;
            }
        }
        __syncthreads();
        if (tid < NBK) bhist[tid * NBH4 + blk] = histS[tid];
        return;
    }
    // encoder: 8 nodes/block, 2 interleaved chains per wave
    for (int i = tid; i < INC * HH; i += 256) Ws[i] = nodeW[i];
    if (tid < HH) bs[tid] = nodeB[tid];
    __syncthreads();
    int wid = tid >> 6, lane = tid & 63;
    int n0 = (bid - NBW - NBH4) * 8 + wid * 2;
    int n1 = n0 + 1;
    bool v0ok = n0 < NN, v1ok = n1 < NN;
    if (!v0ok) return;
    float v0 = (lane < INC) ? x[(size_t)n0 * INC + lane] : 0.f;
    float v1 = (v1ok && lane < INC) ? x[(size_t)n1 * INC + lane] : 0.f;
    float a0 = bs[lane], a1 = a0;
    #pragma unroll
    for (int k = 0; k < INC; ++k) {
        float wv = Ws[k * HH + lane];
        a0 += __shfl(v0, k) * wv;
        a1 += __shfl(v1, k) * wv;
    }
    h[(size_t)n0 * HH + lane] = a0;
    hbf[(size_t)n0 * HH + lane] = f2b(a0);
    if (v1ok) {
        h[(size_t)n1 * HH + lane] = a1;
        hbf[(size_t)n1 * HH + lane] = f2b(a1);
    }
}

// ---------- bucket scan: per-bucket exclusive prefix over blocks + bucket bases ----------
__global__ __launch_bounds__(256) void k_bscan(int* __restrict__ bhist,
                                               int* __restrict__ bbase, int* __restrict__ btot) {
    __shared__ int s[256];
    int t = threadIdx.x;
    int run = 0;
    if (t < NBK) {
        for (int blk = 0; blk < NBH4; ++blk) {
            int v = bhist[t * NBH4 + blk];
            bhist[t * NBH4 + blk] = run;      // exclusive within bucket
            run += v;
        }
    }
    s[t] = (t < NBK) ? run : 0;
    __syncthreads();
    for (int off = 1; off < 256; off <<= 1) {
        int x = (t >= off) ? s[t - off] : 0;
        __syncthreads();
        s[t] += x;
        __syncthreads();
    }
    if (t < NBK) {
        bbase[t] = s[t] - run;                // exclusive bucket base
        btot[t] = run;
    }
}

// ---------- bucket scatter: pos = base + block-prefix + lrank (bijective, NO atomics) ----------
__global__ __launch_bounds__(256) void k_bscatter(const int* __restrict__ src, const int* __restrict__ dst,
                                                  const unsigned short* __restrict__ lrank,
                                                  const int* __restrict__ bhist, const int* __restrict__ bbase,
                                                  int2* __restrict__ pairs) {
    int blk = blockIdx.x;
    int base = blk * 1024 + threadIdx.x;
    #pragma unroll
    for (int k = 0; k < 4; ++k) {
        int e = base + k * 256;
        if (e < NE) {
            int d = dst[e];
            int b = d >> 8;
            int pos = bbase[b] + bhist[b * NBH4 + blk] + (int)lrank[e];
            pairs[pos] = make_int2(src[e], d);
        }
    }
}

// ---------- per-bucket counting sort: emits ssrc rows + meta directly ----------
__global__ __launch_bounds__(256) void k_bsort(const int2* __restrict__ pairs,
                                               const int* __restrict__ bbase, const int* __restrict__ btot,
                                               int* __restrict__ ssrc, int2* __restrict__ meta) {
    __shared__ int cnt[256], s[256], cur[256];
    int b = blockIdx.x, t = threadIdx.x;
    int S = bbase[b], L = btot[b];
    cnt[t] = 0;
    __syncthreads();
    for (int i = S + t; i < S + L; i += 256) atomicAdd(&cnt[pairs[i].y & 255], 1);
    __syncthreads();
    int c = cnt[t];
    s[t] = c;
    __syncthreads();
    for (int off = 1; off < 256; off <<= 1) {
        int x = (t >= off) ? s[t - off] : 0;
        __syncthreads();
        s[t] += x;
        __syncthreads();
    }
    int sst = s[t] - c;      // exclusive slot start within bucket
    cur[t] = sst;
    int node = b * 256 + t;
    if (node < NN) meta[node] = make_int2(S + sst, c);
    __syncthreads();
    for (int i = S + t; i < S + L; i += 256) {
        int2 p = pairs[i];
        int pos = atomicAdd(&cur[p.y & 255], 1);   // LDS atomic
        ssrc[S + pos] = p.x;
    }
}

// ---------- per-dst softmax aggregation: HALF-WAVE per node (256 thr, high occupancy) ----------
// Round-13 lesson: latency-bound, needs ~32 waves/CU; keep standalone.
__global__ __launch_bounds__(256) void k_agg(const float* __restrict__ y,
                                             const unsigned short* __restrict__ ybf,
                                             const int2* __restrict__ meta,
                                             const int* __restrict__ ssrc,
                                             const float* __restrict__ tp,
                                             unsigned short* __restrict__ agh,
                                             unsigned short* __restrict__ agl) {
    int tid = threadIdx.x;
    int w = tid >> 6, lane = tid & 63;
    int half = lane >> 5;
    int l = lane & 31;
    int col = l;
    int n = blockIdx.x * 8 + w * 2 + half;
    bool valid = n < NN;
    float tval = *tp;
    int2 m = valid ? meta[n] : make_int2(0, 0);
    int start = m.x, deg = m.y;

    int dA = __shfl(deg, 0), dB = __shfl(deg, 32);
    int dmax = max(dA, dB);

    float Sa0 = 0.f, Sm0 = 0.f, Sa1 = 0.f, Sm1 = 0.f;
    for (int win = 0; win < dmax; win += 64) {
        int wcnt = min(64, dmax - win);
        int idxLo = (win + l < deg) ? ssrc[start + win + l] : 0;
        int idxHi = (win + 32 + l < deg) ? ssrc[start + win + 32 + l] : 0;
        for (int e0 = 0; e0 < wcnt; e0 += 8) {
            float c0[8], c1[8];
            int ev[8];
            #pragma unroll
            for (int i = 0; i < 8; ++i) {
                int e = e0 + i;
                ev[i] = win + e;
                int sel = (e < 32) ? idxLo : idxHi;
                int s = __shfl(sel, (lane & 32) | (e & 31));
                unsigned v = *(const unsigned*)(ybf + (size_t)s * HH + col * 2);
                c0[i] = b2f((unsigned short)(v & 0xffffu));
                c1[i] = b2f((unsigned short)(v >> 16));
            }
            #pragma unroll
            for (int i = 0; i < 8; ++i) {
                bool ok = ev[i] < deg;
                float m0 = fmaxf(c0[i], 0.f) + MEPS;
                float m1 = fmaxf(c1[i], 0.f) + MEPS;
                float a0 = ok ? __expf(tval * m0) : 0.f;
                float a1 = ok ? __expf(tval * m1) : 0.f;
                Sa0 += a0; Sm0 += m0 * a0;
                Sa1 += a1; Sm1 += m1 * a1;
            }
        }
    }
    if (!valid) return;
    float agg0 = Sm0 / fmaxf(Sa0, MEPS);
    float agg1 = Sm1 / fmaxf(Sa1, MEPS);
    float2 yv = *(const float2*)(y + (size_t)n * HH + col * 2);
    float av0 = agg0 + yv.x;
    float av1 = agg1 + yv.y;
    unsigned short h0 = f2b(av0), h1 = f2b(av1);
    ushort2 ph = {h0, h1};
    ushort2 pl = {f2b(av0 - b2f(h0)), f2b(av1 - b2f(h1))};
    *(ushort2*)(agh + (size_t)n * HH + col * 2) = ph;
    *(ushort2*)(agl + (size_t)n * HH + col * 2) = pl;
}

// ---------- MFMA fused MLP (512 thr / 128 nodes, LDS-staged weights) ----------
// Last layer (lng1==nullptr) fuses outg: LN64 + heads from registers (permuted-head
// MFMA, both operands use the same k-bijection -> exact), h never written.
__global__ __launch_bounds__(512, 4) void k_mlp(
    const unsigned short* __restrict__ agh, const unsigned short* __restrict__ agl,
    const unsigned short* __restrict__ w1h, const unsigned short* __restrict__ w1l,
    const float* __restrict__ b1,
    const float* __restrict__ mlg, const float* __restrict__ mlb,
    const unsigned short* __restrict__ w2h, const unsigned short* __restrict__ w2l,
    const float* __restrict__ b2,
    const float* __restrict__ hres, float* __restrict__ hout,
    const float* __restrict__ lng1, const float* __restrict__ lnb1,
    float* __restrict__ y, unsigned short* __restrict__ ybf,
    const float* __restrict__ lngF, const float* __restrict__ lnbF,
    const unsigned short* __restrict__ whh, const unsigned short* __restrict__ whl,
    const float* __restrict__ bc, float* __restrict__ dout, float* __restrict__ gmax)
{
    __shared__ __align__(16) unsigned short W1S[2 * 128 * 72];  // hi @0, lo @9216; Ut aliases later
    __shared__ __align__(16) unsigned short W2hS[64 * 136];
    __shared__ __align__(16) unsigned short W2lS[64 * 136];
    __shared__ float smax[8][16];
    bool last = (lng1 == nullptr);
    int tid = threadIdx.x;
    int w = tid >> 6, lane = tid & 63;
    int nl = lane & 15, g = lane >> 4;
    int node = blockIdx.x * 128 + w * 16 + nl;
    bool valid = node < NN;

    // ---- issue ag loads FIRST (HBM latency hides under weight staging)
    bf16x8 bAh[2], bAl[2];
    {
        bf16x8 z = {0, 0, 0, 0, 0, 0, 0, 0};
        if (valid) {
            const unsigned short* rp = agh + (size_t)node * HH + g * 8;
            bAh[0] = *(const bf16x8*)rp;
            bAh[1] = *(const bf16x8*)(rp + 32);
            const unsigned short* rq = agl + (size_t)node * HH + g * 8;
            bAl[0] = *(const bf16x8*)rq;
            bAl[1] = *(const bf16x8*)(rq + 32);
        } else {
            bAh[0] = z; bAh[1] = z; bAl[0] = z; bAl[1] = z;
        }
    }

    // ---- cooperative weight staging: 8 coalesced 16B loads/thread
    #pragma unroll
    for (int it = 0; it < 2; ++it) {
        int c = tid + it * 512;
        int row = c >> 3, col = (c & 7) << 3;
        float4 vh = *(const float4*)(w1h + c * 8);
        float4 vl = *(const float4*)(w1l + c * 8);
        *(float4*)&W1S[row * 72 + col] = vh;
        *(float4*)&W1S[9216 + row * 72 + col] = vl;
    }
    #pragma unroll
    for (int it = 0; it < 2; ++it) {
        int c = tid + it * 512;
        int row = c >> 4, col = (c & 15) << 3;
        float4 vh = *(const float4*)(w2h + c * 8);
        float4 vl = *(const float4*)(w2l + c * 8);
        *(float4*)&W2hS[row * 136 + col] = vh;
        *(float4*)&W2lS[row * 136 + col] = vl;
    }
    __syncthreads();

    // ---- gemmA
    f32x4 accU[8];
    #pragma unroll
    for (int t = 0; t < 8; ++t) {
        int uc = t * 16 + g * 4;
        float4 bb = *(const float4*)(b1 + uc);
        f32x4 a = {bb.x, bb.y, bb.z, bb.w};
        #pragma unroll
        for (int kc = 0; kc < 2; ++kc) {
            int wo = (t * 16 + nl) * 72 + kc * 32 + g * 8;
            bf16x8 ah = *(const bf16x8*)&W1S[wo];
            bf16x8 al = *(const bf16x8*)&W1S[9216 + wo];
            a = __builtin_amdgcn_mfma_f32_16x16x32_bf16(ah, bAh[kc], a, 0, 0, 0);
            a = __builtin_amdgcn_mfma_f32_16x16x32_bf16(al, bAh[kc], a, 0, 0, 0);
            a = __builtin_amdgcn_mfma_f32_16x16x32_bf16(ah, bAl[kc], a, 0, 0, 0);
        }
        accU[t] = a;
    }

    // ---- LN(128) lane-local
    float s = 0.f, sq = 0.f;
    #pragma unroll
    for (int t = 0; t < 8; ++t) {
        #pragma unroll
        for (int j = 0; j < 4; ++j) { float v = accU[t][j]; s += v; sq += v * v; }
    }
    s += __shfl_xor(s, 16); sq += __shfl_xor(sq, 16);
    s += __shfl_xor(s, 32); sq += __shfl_xor(sq, 32);
    float mu = s * (1.f / 128.f);
    float var = sq * (1.f / 128.f) - mu * mu;
    float rs = rsqrtf(fmaxf(var, 0.f) + LNE);

    __syncthreads();   // all waves done reading W1 -> Ut may overwrite
    unsigned short* myUt = W1S + w * (16 * 136);

    #pragma unroll
    for (int t = 0; t < 8; ++t) {
        int uc = t * 16 + g * 4;
        float4 gg = *(const float4*)(mlg + uc);
        float4 bb = *(const float4*)(mlb + uc);
        ushort4 pk;
        pk.x = f2b(fmaxf((accU[t][0] - mu) * rs * gg.x + bb.x, 0.f));
        pk.y = f2b(fmaxf((accU[t][1] - mu) * rs * gg.y + bb.y, 0.f));
        pk.z = f2b(fmaxf((accU[t][2] - mu) * rs * gg.z + bb.z, 0.f));
        pk.w = f2b(fmaxf((accU[t][3] - mu) * rs * gg.w + bb.w, 0.f));
        *(ushort4*)(&myUt[nl * 136 + uc]) = pk;
    }
    asm volatile("s_waitcnt lgkmcnt(0)" ::: "memory");

    bf16x8 bB[4];
    #pragma unroll
    for (int kc = 0; kc < 4; ++kc)
        bB[kc] = *(const bf16x8*)(&myUt[nl * 136 + kc * 32 + g * 8]);

    f32x4 accO[4];
    #pragma unroll
    for (int ot = 0; ot < 4; ++ot) {
        int oc = ot * 16 + g * 4;
        float4 bb = *(const float4*)(b2 + oc);
        f32x4 a = {bb.x, bb.y, bb.z, bb.w};
        #pragma unroll
        for (int kc = 0; kc < 4; ++kc) {
            int wo = (ot * 16 + nl) * 136 + kc * 32 + g * 8;
            bf16x8 ah = *(const bf16x8*)&W2hS[wo];
            bf16x8 al = *(const bf16x8*)&W2lS[wo];
            a = __builtin_amdgcn_mfma_f32_16x16x32_bf16(ah, bB[kc], a, 0, 0, 0);
            a = __builtin_amdgcn_mfma_f32_16x16x32_bf16(al, bB[kc], a, 0, 0, 0);
        }
        accO[ot] = a;
    }

    // ---- epilogue: +residual
    float4 oo[4];
    #pragma unroll
    for (int ot = 0; ot < 4; ++ot) {
        int oc = ot * 16 + g * 4;
        float4 o;
        o.x = accO[ot][0]; o.y = accO[ot][1]; o.z = accO[ot][2]; o.w = accO[ot][3];
        if (valid && hres) {
            float4 hr = *(const float4*)(hres + (size_t)node * HH + oc);
            o.x += hr.x; o.y += hr.y; o.z += hr.z; o.w += hr.w;
        }
        oo[ot] = o;
    }

    // shared LN(64) over oo (both branches need it)
    float s2 = 0.f, sq2 = 0.f;
    #pragma unroll
    for (int ot = 0; ot < 4; ++ot) {
        s2 += oo[ot].x + oo[ot].y + oo[ot].z + oo[ot].w;
        sq2 += oo[ot].x * oo[ot].x + oo[ot].y * oo[ot].y
             + oo[ot].z * oo[ot].z + oo[ot].w * oo[ot].w;
    }
    s2 += __shfl_xor(s2, 16); sq2 += __shfl_xor(sq2, 16);
    s2 += __shfl_xor(s2, 32); sq2 += __shfl_xor(sq2, 32);
    float mu2 = s2 * (1.f / 64.f);
    float var2 = sq2 * (1.f / 64.f) - mu2 * mu2;
    float rs2 = rsqrtf(fmaxf(var2, 0.f) + LNE);

    if (!last) {
        #pragma unroll
        for (int ot = 0; ot < 4; ++ot) {
            int oc = ot * 16 + g * 4;
            if (valid) *(float4*)(hout + (size_t)node * HH + oc) = oo[ot];
        }
        #pragma unroll
        for (int ot = 0; ot < 4; ++ot) {
            int oc = ot * 16 + g * 4;
            float4 gg = *(const float4*)(lng1 + oc);
            float4 bb = *(const float4*)(lnb1 + oc);
            float4 v;
            v.x = fmaxf((oo[ot].x - mu2) * rs2 * gg.x + bb.x, 0.f);
            v.y = fmaxf((oo[ot].y - mu2) * rs2 * gg.y + bb.y, 0.f);
            v.z = fmaxf((oo[ot].z - mu2) * rs2 * gg.z + bb.z, 0.f);
            v.w = fmaxf((oo[ot].w - mu2) * rs2 * gg.w + bb.w, 0.f);
            if (valid) {
                *(float4*)(y + (size_t)node * HH + oc) = v;
                ushort4 p;
                p.x = f2b(v.x); p.y = f2b(v.y); p.z = f2b(v.z); p.w = f2b(v.w);
                *(ushort4*)(ybf + (size_t)node * HH + oc) = p;
            }
        }
        return;
    }

    // ---- last layer: fused outg. Permuted-head MFMA: slot (kc,e) of group g holds
    // channel c = (kc*2 + e/4)*16 + g*4 + (e&3); A and B share the bijection -> exact.
    union { bf16x8 v; unsigned short u[8]; } Bh[2], Bl[2];
    #pragma unroll
    for (int kc = 0; kc < 2; ++kc) {
        #pragma unroll
        for (int e = 0; e < 8; ++e) {
            int ot = kc * 2 + (e >> 2);
            int c = ot * 16 + g * 4 + (e & 3);
            float hv = (e & 3) == 0 ? oo[ot].x : ((e & 3) == 1 ? oo[ot].y : ((e & 3) == 2 ? oo[ot].z : oo[ot].w));
            float v = fmaxf((hv - mu2) * rs2 * lngF[c] + lnbF[c], 0.f);
            unsigned short hi = f2b(v);
            Bh[kc].u[e] = hi;
            Bl[kc].u[e] = f2b(v - b2f(hi));
        }
    }
    f32x4 acc[3];
    #pragma unroll
    for (int t = 0; t < 3; ++t) {
        int j0 = t * 16 + g * 4;
        float4 bb = *(const float4*)(bc + j0);
        f32x4 a = {bb.x, bb.y, bb.z, bb.w};
        #pragma unroll
        for (int kc = 0; kc < 2; ++kc) {
            union { bf16x8 v; unsigned short u[8]; } Ah, Al;
            #pragma unroll
            for (int e = 0; e < 8; ++e) {
                int ot = kc * 2 + (e >> 2);
                int c = ot * 16 + g * 4 + (e & 3);
                Ah.u[e] = whh[(size_t)(t * 16 + nl) * 64 + c];
                Al.u[e] = whl[(size_t)(t * 16 + nl) * 64 + c];
            }
            a = __builtin_amdgcn_mfma_f32_16x16x32_bf16(Ah.v, Bh[kc].v, a, 0, 0, 0);
            a = __builtin_amdgcn_mfma_f32_16x16x32_bf16(Al.v, Bh[kc].v, a, 0, 0, 0);
            a = __builtin_amdgcn_mfma_f32_16x16x32_bf16(Ah.v, Bl[kc].v, a, 0, 0, 0);
        }
        acc[t] = a;
    }

    #pragma unroll
    for (int t = 0; t < 3; ++t) {
        #pragma unroll
        for (int reg = 0; reg < 4; ++reg) {
            int j = t * 16 + g * 4 + reg;
            float val = acc[t][reg];
            if (j < ON) {
                if (valid) dout[OC + (size_t)node * ON + j] = val;
            } else if (j < 33) {
                float gv = valid ? val : -INFINITY;
                #pragma unroll
                for (int m = 1; m < 16; m <<= 1) gv = fmaxf(gv, __shfl_xor(gv, m));
                if (nl == 0) smax[w][j - ON] = gv;
            }
        }
    }
    __syncthreads();
    if (tid < 16) {
        float mm = -INFINITY;
        #pragma unroll
        for (int ww = 0; ww < 8; ++ww) mm = fmaxf(mm, smax[ww][tid]);
        gmax[(size_t)blockIdx.x * 16 + tid] = mm;
    }
}

// 1-wave final reduce: gmax[NMB][16] -> dout[0..15]
__global__ void k_gdec(const float* __restrict__ gmax, float* __restrict__ dout) {
    int lane = threadIdx.x & 63;
    int ch = lane & 15, grp = lane >> 4;
    float m = -INFINITY;
    for (int b = grp; b < NMB; b += 4) m = fmaxf(m, gmax[(size_t)b * 16 + ch]);
    m = fmaxf(m, __shfl_xor(m, 16));
    m = fmaxf(m, __shfl_xor(m, 32));
    if (lane < 16) dout[ch] = m;
}

// ---------- launch ----------
extern "C" void kernel_launch(void* const* d_in, const int* in_sizes, int n_in,
                              void* d_out, int out_size, void* d_ws, size_t ws_size,
                              hipStream_t stream) {
    const float* x     = (const float*)d_in[0];
    const float* nodeW = (const float*)d_in[1];
    const float* nodeB = (const float*)d_in[2];
    const float* W1    = (const float*)d_in[3];
    const float* b1    = (const float*)d_in[4];
    const float* mlg   = (const float*)d_in[5];
    const float* mlb   = (const float*)d_in[6];
    const float* W2    = (const float*)d_in[7];
    const float* b2    = (const float*)d_in[8];
    const float* tt    = (const float*)d_in[9];
    const float* lng   = (const float*)d_in[10];
    const float* lnb   = (const float*)d_in[11];
    const int*   ei    = (const int*)d_in[12];
    const float* gW    = (const float*)d_in[13];
    const float* gb    = (const float*)d_in[14];
    const float* nW    = (const float*)d_in[15];
    const float* nbp   = (const float*)d_in[16];
    float* out = (float*)d_out;

    char* ws = (char*)d_ws;
    size_t off = 0;
    auto alloc = [&](size_t bytes) -> void* {
        void* p = ws + off;
        off = (off + bytes + 255) & ~(size_t)255;
        return p;
    };
    int* bhist = (int*)alloc((size_t)NBK * NBH4 * 4);   // fully written by k_pre
    int* bbase = (int*)alloc((size_t)NBK * 4);
    int* btot  = (int*)alloc((size_t)NBK * 4);
    float* gmax = (float*)alloc((size_t)NMB * 16 * 4);
    int2* meta = (int2*)alloc((size_t)NN * 8);
    int* ssrc  = (int*)alloc((size_t)NE * 4);
    float* h   = (float*)alloc((size_t)NN * HH * 4);
    float* y   = (float*)alloc((size_t)NN * HH * 4);
    unsigned short* agh = (unsigned short*)alloc((size_t)NN * HH * 2);
    unsigned short* agl = (unsigned short*)alloc((size_t)NN * HH * 2);
    unsigned short* ybf = (unsigned short*)alloc((size_t)NN * HH * 2);
    unsigned short* w1h = (unsigned short*)alloc((size_t)NL * H2 * HH * 2);
    unsigned short* w1l = (unsigned short*)alloc((size_t)NL * H2 * HH * 2);
    unsigned short* w2h = (unsigned short*)alloc((size_t)NL * H2 * HH * 2);
    unsigned short* w2l = (unsigned short*)alloc((size_t)NL * H2 * HH * 2);
    unsigned short* whh = (unsigned short*)alloc((size_t)48 * 64 * 2);
    unsigned short* whl = (unsigned short*)alloc((size_t)48 * 64 * 2);
    float* bc = (float*)alloc(48 * 4);
    // aliases: lrank lives only during CSR build (agh first written at agg layer 0);
    //          pairs lives only during CSR build (y first written at mlp layer 0, 6.4MB <= 12.8MB)
    unsigned short* lrank = (unsigned short*)agh;
    int2* pairs = (int2*)y;

    const int* esrc = ei;
    const int* edst = ei + NE;

    k_pre<<<NBW + NBH4 + NBE8, 256, 0, stream>>>(W1, W2, nW, gW, nbp, gb,
                                                 w1h, w1l, w2h, w2l, whh, whl, bc,
                                                 edst, bhist, lrank,
                                                 x, nodeW, nodeB, h, ybf);
    k_bscan<<<1, 256, 0, stream>>>(bhist, bbase, btot);
    k_bscatter<<<NBH4, 256, 0, stream>>>(esrc, edst, lrank, bhist, bbase, pairs);
    k_bsort<<<NBK, 256, 0, stream>>>(pairs, bbase, btot, ssrc, meta);

    for (int l = 0; l < NL; ++l) {
        const float* yin = (l == 0) ? h : y;
        k_agg<<<(NN + 7) / 8, 256, 0, stream>>>(yin, ybf, meta, ssrc, tt + l, agh, agl);
        bool lastL = (l == NL - 1);
        const float* ln1g = lastL ? nullptr : (lng + (size_t)(l + 1) * HH);
        const float* ln1b = lastL ? nullptr : (lnb + (size_t)(l + 1) * HH);
        k_mlp<<<NMB, 512, 0, stream>>>(agh, agl,
                                       w1h + (size_t)l * H2 * HH, w1l + (size_t)l * H2 * HH,
                                       b1 + (size_t)l * H2,
                                       mlg + (size_t)l * H2, mlb + (size_t)l * H2,
                                       w2h + (size_t)l * H2 * HH, w2l + (size_t)l * H2 * HH,
                                       b2 + (size_t)l * HH,
                                       (l == 0) ? (const float*)nullptr : h, h,
                                       ln1g, ln1b, y, ybf,
                                       lng, lnb, whh, whl, bc, out, gmax);
    }
    k_gdec<<<1, 64, 0, stream>>>(gmax, out);
}

// Round 18
// 351.434 us; speedup vs baseline: 1.1562x; 1.1562x over previous
//
#include <hip/hip_runtime.h>

#define NN 50000
#define NE 800000
#define INC 32
#define HH 64
#define H2 128
#define OC 16
#define ON 17
#define NL 4
#define MEPS 1e-7f
#define LNE 1e-5f
#define NMB ((NN + 127) / 128)     /* k_mlp blocks = 391 */
#define NBW ((NL * H2 * HH + 255) / 256)   /* 128 */
#define NBH4 ((NE + 1023) / 1024)          /* 782: hist/scatter blocks, 4 edges/thread */
#define NBE8 ((NN + 7) / 8)                /* 6250: encoder, 8 nodes/block */
#define NBK  ((NN + 255) / 256)            /* 196 dst-buckets */

typedef __attribute__((ext_vector_type(8))) short bf16x8;
typedef __attribute__((ext_vector_type(4))) float f32x4;

// ---------- bf16 helpers (RNE) ----------
__device__ __forceinline__ unsigned short f2b(float x) {
    unsigned b = __float_as_uint(x);
    b += 0x7FFFu + ((b >> 16) & 1u);
    return (unsigned short)(b >> 16);
}
__device__ __forceinline__ float b2f(unsigned short u) {
    return __uint_as_float(((unsigned)u) << 16);
}

// ---------- fused pre-pass: wprep | LDS-hist (NO global atomics) | encoder ----------
__global__ __launch_bounds__(256) void k_pre(
    const float* __restrict__ W1, const float* __restrict__ W2,
    const float* __restrict__ nW, const float* __restrict__ gW,
    const float* __restrict__ nbp, const float* __restrict__ gb,
    unsigned short* __restrict__ w1h, unsigned short* __restrict__ w1l,
    unsigned short* __restrict__ w2h, unsigned short* __restrict__ w2l,
    unsigned short* __restrict__ whh, unsigned short* __restrict__ whl,
    float* __restrict__ bc,
    const int* __restrict__ edst, int* __restrict__ bhist, unsigned short* __restrict__ lrank,
    const float* __restrict__ x, const float* __restrict__ nodeW,
    const float* __restrict__ nodeB, float* __restrict__ h,
    unsigned short* __restrict__ hbf)
{
    __shared__ float Ws[INC * HH];
    __shared__ float bs[HH];
    __shared__ int histS[256];
    int bid = blockIdx.x, tid = threadIdx.x;
    if (bid < NBW) {
        int i = bid * 256 + tid;
        if (i < 48 * 64) {
            int j = i >> 6, k = i & 63;
            float v = 0.f;
            if (j < ON) v = nW[k * ON + j];
            else if (j < 33) v = gW[k * OC + (j - ON)];
            unsigned short hi = f2b(v);
            whh[i] = hi;
            whl[i] = f2b(v - b2f(hi));
        }
        if (i < 48) bc[i] = (i < ON) ? nbp[i] : ((i < 33) ? gb[i - ON] : 0.f);
        if (i >= NL * H2 * HH) return;
        int l = i / (H2 * HH), r = i % (H2 * HH);
        {
            int c = r / HH, k = r % HH;
            float v = W1[(size_t)l * HH * H2 + (size_t)k * H2 + c];
            unsigned short hi = f2b(v);
            w1h[i] = hi;
            w1l[i] = f2b(v - b2f(hi));
        }
        {
            int c = r / H2, k = r % H2;
            float v = W2[(size_t)l * H2 * HH + (size_t)k * HH + c];
            unsigned short hi = f2b(v);
            w2h[i] = hi;
            w2l[i] = f2b(v - b2f(hi));
        }
        return;
    }
    if (bid < NBW + NBH4) {
        int blk = bid - NBW;
        histS[tid] = 0;
        __syncthreads();
        int base = blk * 1024 + tid;
        #pragma unroll
        for (int k = 0; k < 4; ++k) {
            int e = base + k * 256;
            if (e < NE) {
                int r = atomicAdd(&histS[edst[e] >> 8], 1);   // LDS atomic: cheap
                lrank[e] = (unsigned short)r;
            }
        }
        __syncthreads();
        if (tid < NBK) bhist[tid * NBH4 + blk] = histS[tid];
        return;
    }
    // encoder: 8 nodes/block, 2 interleaved chains per wave
    for (int i = tid; i < INC * HH; i += 256) Ws[i] = nodeW[i];
    if (tid < HH) bs[tid] = nodeB[tid];
    __syncthreads();
    int wid = tid >> 6, lane = tid & 63;
    int n0 = (bid - NBW - NBH4) * 8 + wid * 2;
    int n1 = n0 + 1;
    bool v0ok = n0 < NN, v1ok = n1 < NN;
    if (!v0ok) return;
    float v0 = (lane < INC) ? x[(size_t)n0 * INC + lane] : 0.f;
    float v1 = (v1ok && lane < INC) ? x[(size_t)n1 * INC + lane] : 0.f;
    float a0 = bs[lane], a1 = a0;
    #pragma unroll
    for (int k = 0; k < INC; ++k) {
        float wv = Ws[k * HH + lane];
        a0 += __shfl(v0, k) * wv;
        a1 += __shfl(v1, k) * wv;
    }
    h[(size_t)n0 * HH + lane] = a0;
    hbf[(size_t)n0 * HH + lane] = f2b(a0);
    if (v1ok) {
        h[(size_t)n1 * HH + lane] = a1;
        hbf[(size_t)n1 * HH + lane] = f2b(a1);
    }
}

// ---------- bucket scan A: 196 blocks, each scans its bucket's 782 block-counts ----------
// (round-17 lesson: the 1-block serial version was 67us at 0.04% occupancy)
__global__ __launch_bounds__(256) void k_bscanA(int* __restrict__ bhist, int* __restrict__ btot) {
    __shared__ int s[256];
    int b = blockIdx.x, t = threadIdx.x;
    int base = t * 4;
    int v[4];
    int sum = 0;
    #pragma unroll
    for (int k = 0; k < 4; ++k) {
        int idx = base + k;
        v[k] = (idx < NBH4) ? bhist[(size_t)b * NBH4 + idx] : 0;
        sum += v[k];
    }
    s[t] = sum;
    __syncthreads();
    for (int off = 1; off < 256; off <<= 1) {
        int x = (t >= off) ? s[t - off] : 0;
        __syncthreads();
        s[t] += x;
        __syncthreads();
    }
    int run = s[t] - sum;   // exclusive over chunks
    #pragma unroll
    for (int k = 0; k < 4; ++k) {
        int idx = base + k;
        if (idx < NBH4) { bhist[(size_t)b * NBH4 + idx] = run; run += v[k]; }
    }
    if (t == 255) btot[b] = s[255];
}

// ---------- bucket scan B: exclusive scan of 196 bucket totals -> bases ----------
__global__ __launch_bounds__(256) void k_bscanB(const int* __restrict__ btot, int* __restrict__ bbase) {
    __shared__ int s[256];
    int t = threadIdx.x;
    int v = (t < NBK) ? btot[t] : 0;
    s[t] = v;
    __syncthreads();
    for (int off = 1; off < 256; off <<= 1) {
        int x = (t >= off) ? s[t - off] : 0;
        __syncthreads();
        s[t] += x;
        __syncthreads();
    }
    if (t < NBK) bbase[t] = s[t] - v;
}

// ---------- bucket scatter: pos = base + block-prefix + lrank (bijective, NO atomics) ----------
__global__ __launch_bounds__(256) void k_bscatter(const int* __restrict__ src, const int* __restrict__ dst,
                                                  const unsigned short* __restrict__ lrank,
                                                  const int* __restrict__ bhist, const int* __restrict__ bbase,
                                                  int2* __restrict__ pairs) {
    int blk = blockIdx.x;
    int base = blk * 1024 + threadIdx.x;
    #pragma unroll
    for (int k = 0; k < 4; ++k) {
        int e = base + k * 256;
        if (e < NE) {
            int d = dst[e];
            int b = d >> 8;
            int pos = bbase[b] + bhist[(size_t)b * NBH4 + blk] + (int)lrank[e];
            pairs[pos] = make_int2(src[e], d);
        }
    }
}

// ---------- per-bucket counting sort: emits ssrc rows + meta directly ----------
__global__ __launch_bounds__(256) void k_bsort(const int2* __restrict__ pairs,
                                               const int* __restrict__ bbase, const int* __restrict__ btot,
                                               int* __restrict__ ssrc, int2* __restrict__ meta) {
    __shared__ int cnt[256], s[256], cur[256];
    int b = blockIdx.x, t = threadIdx.x;
    int S = bbase[b], L = btot[b];
    cnt[t] = 0;
    __syncthreads();
    for (int i = S + t; i < S + L; i += 256) atomicAdd(&cnt[pairs[i].y & 255], 1);
    __syncthreads();
    int c = cnt[t];
    s[t] = c;
    __syncthreads();
    for (int off = 1; off < 256; off <<= 1) {
        int x = (t >= off) ? s[t - off] : 0;
        __syncthreads();
        s[t] += x;
        __syncthreads();
    }
    int sst = s[t] - c;      // exclusive slot start within bucket
    cur[t] = sst;
    int node = b * 256 + t;
    if (node < NN) meta[node] = make_int2(S + sst, c);
    __syncthreads();
    for (int i = S + t; i < S + L; i += 256) {
        int2 p = pairs[i];
        int pos = atomicAdd(&cur[p.y & 255], 1);   // LDS atomic
        ssrc[S + pos] = p.x;
    }
}

// ---------- per-dst softmax aggregation: HALF-WAVE per node (256 thr, high occupancy) ----------
__global__ __launch_bounds__(256) void k_agg(const float* __restrict__ y,
                                             const unsigned short* __restrict__ ybf,
                                             const int2* __restrict__ meta,
                                             const int* __restrict__ ssrc,
                                             const float* __restrict__ tp,
                                             unsigned short* __restrict__ agh,
                                             unsigned short* __restrict__ agl) {
    int tid = threadIdx.x;
    int w = tid >> 6, lane = tid & 63;
    int half = lane >> 5;
    int l = lane & 31;
    int col = l;
    int n = blockIdx.x * 8 + w * 2 + half;
    bool valid = n < NN;
    float tval = *tp;
    int2 m = valid ? meta[n] : make_int2(0, 0);
    int start = m.x, deg = m.y;

    int dA = __shfl(deg, 0), dB = __shfl(deg, 32);
    int dmax = max(dA, dB);

    float Sa0 = 0.f, Sm0 = 0.f, Sa1 = 0.f, Sm1 = 0.f;
    for (int win = 0; win < dmax; win += 64) {
        int wcnt = min(64, dmax - win);
        int idxLo = (win + l < deg) ? ssrc[start + win + l] : 0;
        int idxHi = (win + 32 + l < deg) ? ssrc[start + win + 32 + l] : 0;
        for (int e0 = 0; e0 < wcnt; e0 += 8) {
            float c0[8], c1[8];
            int ev[8];
            #pragma unroll
            for (int i = 0; i < 8; ++i) {
                int e = e0 + i;
                ev[i] = win + e;
                int sel = (e < 32) ? idxLo : idxHi;
                int s = __shfl(sel, (lane & 32) | (e & 31));
                unsigned v = *(const unsigned*)(ybf + (size_t)s * HH + col * 2);
                c0[i] = b2f((unsigned short)(v & 0xffffu));
                c1[i] = b2f((unsigned short)(v >> 16));
            }
            #pragma unroll
            for (int i = 0; i < 8; ++i) {
                bool ok = ev[i] < deg;
                float m0 = fmaxf(c0[i], 0.f) + MEPS;
                float m1 = fmaxf(c1[i], 0.f) + MEPS;
                float a0 = ok ? __expf(tval * m0) : 0.f;
                float a1 = ok ? __expf(tval * m1) : 0.f;
                Sa0 += a0; Sm0 += m0 * a0;
                Sa1 += a1; Sm1 += m1 * a1;
            }
        }
    }
    if (!valid) return;
    float agg0 = Sm0 / fmaxf(Sa0, MEPS);
    float agg1 = Sm1 / fmaxf(Sa1, MEPS);
    float2 yv = *(const float2*)(y + (size_t)n * HH + col * 2);
    float av0 = agg0 + yv.x;
    float av1 = agg1 + yv.y;
    unsigned short h0 = f2b(av0), h1 = f2b(av1);
    ushort2 ph = {h0, h1};
    ushort2 pl = {f2b(av0 - b2f(h0)), f2b(av1 - b2f(h1))};
    *(ushort2*)(agh + (size_t)n * HH + col * 2) = ph;
    *(ushort2*)(agl + (size_t)n * HH + col * 2) = pl;
}

// ---------- MFMA fused MLP (512 thr / 128 nodes, LDS-staged weights) ----------
__global__ __launch_bounds__(512, 4) void k_mlp(
    const unsigned short* __restrict__ agh, const unsigned short* __restrict__ agl,
    const unsigned short* __restrict__ w1h, const unsigned short* __restrict__ w1l,
    const float* __restrict__ b1,
    const float* __restrict__ mlg, const float* __restrict__ mlb,
    const unsigned short* __restrict__ w2h, const unsigned short* __restrict__ w2l,
    const float* __restrict__ b2,
    const float* __restrict__ hres, float* __restrict__ hout,
    const float* __restrict__ lng1, const float* __restrict__ lnb1,
    float* __restrict__ y, unsigned short* __restrict__ ybf,
    const float* __restrict__ lngF, const float* __restrict__ lnbF,
    const unsigned short* __restrict__ whh, const unsigned short* __restrict__ whl,
    const float* __restrict__ bc, float* __restrict__ dout, float* __restrict__ gmax)
{
    __shared__ __align__(16) unsigned short W1S[2 * 128 * 72];  // hi @0, lo @9216; Ut aliases later
    __shared__ __align__(16) unsigned short W2hS[64 * 136];
    __shared__ __align__(16) unsigned short W2lS[64 * 136];
    __shared__ float smax[8][16];
    bool last = (lng1 == nullptr);
    int tid = threadIdx.x;
    int w = tid >> 6, lane = tid & 63;
    int nl = lane & 15, g = lane >> 4;
    int node = blockIdx.x * 128 + w * 16 + nl;
    bool valid = node < NN;

    // ---- issue ag loads FIRST (HBM latency hides under weight staging)
    bf16x8 bAh[2], bAl[2];
    {
        bf16x8 z = {0, 0, 0, 0, 0, 0, 0, 0};
        if (valid) {
            const unsigned short* rp = agh + (size_t)node * HH + g * 8;
            bAh[0] = *(const bf16x8*)rp;
            bAh[1] = *(const bf16x8*)(rp + 32);
            const unsigned short* rq = agl + (size_t)node * HH + g * 8;
            bAl[0] = *(const bf16x8*)rq;
            bAl[1] = *(const bf16x8*)(rq + 32);
        } else {
            bAh[0] = z; bAh[1] = z; bAl[0] = z; bAl[1] = z;
        }
    }

    // ---- cooperative weight staging: 8 coalesced 16B loads/thread
    #pragma unroll
    for (int it = 0; it < 2; ++it) {
        int c = tid + it * 512;
        int row = c >> 3, col = (c & 7) << 3;
        float4 vh = *(const float4*)(w1h + c * 8);
        float4 vl = *(const float4*)(w1l + c * 8);
        *(float4*)&W1S[row * 72 + col] = vh;
        *(float4*)&W1S[9216 + row * 72 + col] = vl;
    }
    #pragma unroll
    for (int it = 0; it < 2; ++it) {
        int c = tid + it * 512;
        int row = c >> 4, col = (c & 15) << 3;
        float4 vh = *(const float4*)(w2h + c * 8);
        float4 vl = *(const float4*)(w2l + c * 8);
        *(float4*)&W2hS[row * 136 + col] = vh;
        *(float4*)&W2lS[row * 136 + col] = vl;
    }
    __syncthreads();

    // ---- gemmA
    f32x4 accU[8];
    #pragma unroll
    for (int t = 0; t < 8; ++t) {
        int uc = t * 16 + g * 4;
        float4 bb = *(const float4*)(b1 + uc);
        f32x4 a = {bb.x, bb.y, bb.z, bb.w};
        #pragma unroll
        for (int kc = 0; kc < 2; ++kc) {
            int wo = (t * 16 + nl) * 72 + kc * 32 + g * 8;
            bf16x8 ah = *(const bf16x8*)&W1S[wo];
            bf16x8 al = *(const bf16x8*)&W1S[9216 + wo];
            a = __builtin_amdgcn_mfma_f32_16x16x32_bf16(ah, bAh[kc], a, 0, 0, 0);
            a = __builtin_amdgcn_mfma_f32_16x16x32_bf16(al, bAh[kc], a, 0, 0, 0);
            a = __builtin_amdgcn_mfma_f32_16x16x32_bf16(ah, bAl[kc], a, 0, 0, 0);
        }
        accU[t] = a;
    }

    // ---- LN(128) lane-local
    float s = 0.f, sq = 0.f;
    #pragma unroll
    for (int t = 0; t < 8; ++t) {
        #pragma unroll
        for (int j = 0; j < 4; ++j) { float v = accU[t][j]; s += v; sq += v * v; }
    }
    s += __shfl_xor(s, 16); sq += __shfl_xor(sq, 16);
    s += __shfl_xor(s, 32); sq += __shfl_xor(sq, 32);
    float mu = s * (1.f / 128.f);
    float var = sq * (1.f / 128.f) - mu * mu;
    float rs = rsqrtf(fmaxf(var, 0.f) + LNE);

    __syncthreads();   // all waves done reading W1 -> Ut may overwrite
    unsigned short* myUt = W1S + w * (16 * 136);

    #pragma unroll
    for (int t = 0; t < 8; ++t) {
        int uc = t * 16 + g * 4;
        float4 gg = *(const float4*)(mlg + uc);
        float4 bb = *(const float4*)(mlb + uc);
        ushort4 pk;
        pk.x = f2b(fmaxf((accU[t][0] - mu) * rs * gg.x + bb.x, 0.f));
        pk.y = f2b(fmaxf((accU[t][1] - mu) * rs * gg.y + bb.y, 0.f));
        pk.z = f2b(fmaxf((accU[t][2] - mu) * rs * gg.z + bb.z, 0.f));
        pk.w = f2b(fmaxf((accU[t][3] - mu) * rs * gg.w + bb.w, 0.f));
        *(ushort4*)(&myUt[nl * 136 + uc]) = pk;
    }
    asm volatile("s_waitcnt lgkmcnt(0)" ::: "memory");

    bf16x8 bB[4];
    #pragma unroll
    for (int kc = 0; kc < 4; ++kc)
        bB[kc] = *(const bf16x8*)(&myUt[nl * 136 + kc * 32 + g * 8]);

    f32x4 accO[4];
    #pragma unroll
    for (int ot = 0; ot < 4; ++ot) {
        int oc = ot * 16 + g * 4;
        float4 bb = *(const float4*)(b2 + oc);
        f32x4 a = {bb.x, bb.y, bb.z, bb.w};
        #pragma unroll
        for (int kc = 0; kc < 4; ++kc) {
            int wo = (ot * 16 + nl) * 136 + kc * 32 + g * 8;
            bf16x8 ah = *(const bf16x8*)&W2hS[wo];
            bf16x8 al = *(const bf16x8*)&W2lS[wo];
            a = __builtin_amdgcn_mfma_f32_16x16x32_bf16(ah, bB[kc], a, 0, 0, 0);
            a = __builtin_amdgcn_mfma_f32_16x16x32_bf16(al, bB[kc], a, 0, 0, 0);
        }
        accO[ot] = a;
    }

    // ---- epilogue: +residual
    float4 oo[4];
    #pragma unroll
    for (int ot = 0; ot < 4; ++ot) {
        int oc = ot * 16 + g * 4;
        float4 o;
        o.x = accO[ot][0]; o.y = accO[ot][1]; o.z = accO[ot][2]; o.w = accO[ot][3];
        if (valid && hres) {
            float4 hr = *(const float4*)(hres + (size_t)node * HH + oc);
            o.x += hr.x; o.y += hr.y; o.z += hr.z; o.w += hr.w;
        }
        oo[ot] = o;
    }

    // shared LN(64) over oo (both branches need it)
    float s2 = 0.f, sq2 = 0.f;
    #pragma unroll
    for (int ot = 0; ot < 4; ++ot) {
        s2 += oo[ot].x + oo[ot].y + oo[ot].z + oo[ot].w;
        sq2 += oo[ot].x * oo[ot].x + oo[ot].y * oo[ot].y
             + oo[ot].z * oo[ot].z + oo[ot].w * oo[ot].w;
    }
    s2 += __shfl_xor(s2, 16); sq2 += __shfl_xor(sq2, 16);
    s2 += __shfl_xor(s2, 32); sq2 += __shfl_xor(sq2, 32);
    float mu2 = s2 * (1.f / 64.f);
    float var2 = sq2 * (1.f / 64.f) - mu2 * mu2;
    float rs2 = rsqrtf(fmaxf(var2, 0.f) + LNE);

    if (!last) {
        #pragma unroll
        for (int ot = 0; ot < 4; ++ot) {
            int oc = ot * 16 + g * 4;
            if (valid) *(float4*)(hout + (size_t)node * HH + oc) = oo[ot];
        }
        #pragma unroll
        for (int ot = 0; ot < 4; ++ot) {
            int oc = ot * 16 + g * 4;
            float4 gg = *(const float4*)(lng1 + oc);
            float4 bb = *(const float4*)(lnb1 + oc);
            float4 v;
            v.x = fmaxf((oo[ot].x - mu2) * rs2 * gg.x + bb.x, 0.f);
            v.y = fmaxf((oo[ot].y - mu2) * rs2 * gg.y + bb.y, 0.f);
            v.z = fmaxf((oo[ot].z - mu2) * rs2 * gg.z + bb.z, 0.f);
            v.w = fmaxf((oo[ot].w - mu2) * rs2 * gg.w + bb.w, 0.f);
            if (valid) {
                *(float4*)(y + (size_t)node * HH + oc) = v;
                ushort4 p;
                p.x = f2b(v.x); p.y = f2b(v.y); p.z = f2b(v.z); p.w = f2b(v.w);
                *(ushort4*)(ybf + (size_t)node * HH + oc) = p;
            }
        }
        return;
    }

    // ---- last layer: fused outg. Permuted-head MFMA: slot (kc,e) of group g holds
    // channel c = (kc*2 + e/4)*16 + g*4 + (e&3); A and B share the bijection -> exact.
    union { bf16x8 v; unsigned short u[8]; } Bh[2], Bl[2];
    #pragma unroll
    for (int kc = 0; kc < 2; ++kc) {
        #pragma unroll
        for (int e = 0; e < 8; ++e) {
            int ot = kc * 2 + (e >> 2);
            int c = ot * 16 + g * 4 + (e & 3);
            float hv = (e & 3) == 0 ? oo[ot].x : ((e & 3) == 1 ? oo[ot].y : ((e & 3) == 2 ? oo[ot].z : oo[ot].w));
            float v = fmaxf((hv - mu2) * rs2 * lngF[c] + lnbF[c], 0.f);
            unsigned short hi = f2b(v);
            Bh[kc].u[e] = hi;
            Bl[kc].u[e] = f2b(v - b2f(hi));
        }
    }
    f32x4 acc[3];
    #pragma unroll
    for (int t = 0; t < 3; ++t) {
        int j0 = t * 16 + g * 4;
        float4 bb = *(const float4*)(bc + j0);
        f32x4 a = {bb.x, bb.y, bb.z, bb.w};
        #pragma unroll
        for (int kc = 0; kc < 2; ++kc) {
            union { bf16x8 v; unsigned short u[8]; } Ah, Al;
            #pragma unroll
            for (int e = 0; e < 8; ++e) {
                int ot = kc * 2 + (e >> 2);
                int c = ot * 16 + g * 4 + (e & 3);
                Ah.u[e] = whh[(size_t)(t * 16 + nl) * 64 + c];
                Al.u[e] = whl[(size_t)(t * 16 + nl) * 64 + c];
            }
            a = __builtin_amdgcn_mfma_f32_16x16x32_bf16(Ah.v, Bh[kc].v, a, 0, 0, 0);
            a = __builtin_amdgcn_mfma_f32_16x16x32_bf16(Al.v, Bh[kc].v, a, 0, 0, 0);
            a = __builtin_amdgcn_mfma_f32_16x16x32_bf16(Ah.v, Bl[kc].v, a, 0, 0, 0);
        }
        acc[t] = a;
    }

    #pragma unroll
    for (int t = 0; t < 3; ++t) {
        #pragma unroll
        for (int reg = 0; reg < 4; ++reg) {
            int j = t * 16 + g * 4 + reg;
            float val = acc[t][reg];
            if (j < ON) {
                if (valid) dout[OC + (size_t)node * ON + j] = val;
            } else if (j < 33) {
                float gv = valid ? val : -INFINITY;
                #pragma unroll
                for (int m = 1; m < 16; m <<= 1) gv = fmaxf(gv, __shfl_xor(gv, m));
                if (nl == 0) smax[w][j - ON] = gv;
            }
        }
    }
    __syncthreads();
    if (tid < 16) {
        float mm = -INFINITY;
        #pragma unroll
        for (int ww = 0; ww < 8; ++ww) mm = fmaxf(mm, smax[ww][tid]);
        gmax[(size_t)blockIdx.x * 16 + tid] = mm;
    }
}

// 1-wave final reduce: gmax[NMB][16] -> dout[0..15]
__global__ void k_gdec(const float* __restrict__ gmax, float* __restrict__ dout) {
    int lane = threadIdx.x & 63;
    int ch = lane & 15, grp = lane >> 4;
    float m = -INFINITY;
    for (int b = grp; b < NMB; b += 4) m = fmaxf(m, gmax[(size_t)b * 16 + ch]);
    m = fmaxf(m, __shfl_xor(m, 16));
    m = fmaxf(m, __shfl_xor(m, 32));
    if (lane < 16) dout[ch] = m;
}

// ---------- launch ----------
extern "C" void kernel_launch(void* const* d_in, const int* in_sizes, int n_in,
                              void* d_out, int out_size, void* d_ws, size_t ws_size,
                              hipStream_t stream) {
    const float* x     = (const float*)d_in[0];
    const float* nodeW = (const float*)d_in[1];
    const float* nodeB = (const float*)d_in[2];
    const float* W1    = (const float*)d_in[3];
    const float* b1    = (const float*)d_in[4];
    const float* mlg   = (const float*)d_in[5];
    const float* mlb   = (const float*)d_in[6];
    const float* W2    = (const float*)d_in[7];
    const float* b2    = (const float*)d_in[8];
    const float* tt    = (const float*)d_in[9];
    const float* lng   = (const float*)d_in[10];
    const float* lnb   = (const float*)d_in[11];
    const int*   ei    = (const int*)d_in[12];
    const float* gW    = (const float*)d_in[13];
    const float* gb    = (const float*)d_in[14];
    const float* nW    = (const float*)d_in[15];
    const float* nbp   = (const float*)d_in[16];
    float* out = (float*)d_out;

    char* ws = (char*)d_ws;
    size_t off = 0;
    auto alloc = [&](size_t bytes) -> void* {
        void* p = ws + off;
        off = (off + bytes + 255) & ~(size_t)255;
        return p;
    };
    int* bhist = (int*)alloc((size_t)NBK * NBH4 * 4);   // fully written by k_pre
    int* bbase = (int*)alloc((size_t)NBK * 4);
    int* btot  = (int*)alloc((size_t)NBK * 4);
    float* gmax = (float*)alloc((size_t)NMB * 16 * 4);
    int2* meta = (int2*)alloc((size_t)NN * 8);
    int* ssrc  = (int*)alloc((size_t)NE * 4);
    float* h   = (float*)alloc((size_t)NN * HH * 4);
    float* y   = (float*)alloc((size_t)NN * HH * 4);
    unsigned short* agh = (unsigned short*)alloc((size_t)NN * HH * 2);
    unsigned short* agl = (unsigned short*)alloc((size_t)NN * HH * 2);
    unsigned short* ybf = (unsigned short*)alloc((size_t)NN * HH * 2);
    unsigned short* w1h = (unsigned short*)alloc((size_t)NL * H2 * HH * 2);
    unsigned short* w1l = (unsigned short*)alloc((size_t)NL * H2 * HH * 2);
    unsigned short* w2h = (unsigned short*)alloc((size_t)NL * H2 * HH * 2);
    unsigned short* w2l = (unsigned short*)alloc((size_t)NL * H2 * HH * 2);
    unsigned short* whh = (unsigned short*)alloc((size_t)48 * 64 * 2);
    unsigned short* whl = (unsigned short*)alloc((size_t)48 * 64 * 2);
    float* bc = (float*)alloc(48 * 4);
    // aliases: lrank lives only during CSR build (agh first written at agg layer 0);
    //          pairs lives only during CSR build (y first written at mlp layer 0)
    unsigned short* lrank = (unsigned short*)agh;
    int2* pairs = (int2*)y;

    const int* esrc = ei;
    const int* edst = ei + NE;

    k_pre<<<NBW + NBH4 + NBE8, 256, 0, stream>>>(W1, W2, nW, gW, nbp, gb,
                                                 w1h, w1l, w2h, w2l, whh, whl, bc,
                                                 edst, bhist, lrank,
                                                 x, nodeW, nodeB, h, ybf);
    k_bscanA<<<NBK, 256, 0, stream>>>(bhist, btot);
    k_bscanB<<<1, 256, 0, stream>>>(btot, bbase);
    k_bscatter<<<NBH4, 256, 0, stream>>>(esrc, edst, lrank, bhist, bbase, pairs);
    k_bsort<<<NBK, 256, 0, stream>>>(pairs, bbase, btot, ssrc, meta);

    for (int l = 0; l < NL; ++l) {
        const float* yin = (l == 0) ? h : y;
        k_agg<<<(NN + 7) / 8, 256, 0, stream>>>(yin, ybf, meta, ssrc, tt + l, agh, agl);
        bool lastL = (l == NL - 1);
        const float* ln1g = lastL ? nullptr : (lng + (size_t)(l + 1) * HH);
        const float* ln1b = lastL ? nullptr : (lnb + (size_t)(l + 1) * HH);
        k_mlp<<<NMB, 512, 0, stream>>>(agh, agl,
                                       w1h + (size_t)l * H2 * HH, w1l + (size_t)l * H2 * HH,
                                       b1 + (size_t)l * H2,
                                       mlg + (size_t)l * H2, mlb + (size_t)l * H2,
                                       w2h + (size_t)l * H2 * HH, w2l + (size_t)l * H2 * HH,
                                       b2 + (size_t)l * HH,
                                       (l == 0) ? (const float*)nullptr : h, h,
                                       ln1g, ln1b, y, ybf,
                                       lng, lnb, whh, whl, bc, out, gmax);
    }
    k_gdec<<<1, 64, 0, stream>>>(gmax, out);
}